// Round 2
// baseline (575.541 us; speedup 1.0000x reference)
//
#include <hip/hip_runtime.h>

// Flow-warp bilinear resample with TF safe-gather + OOB masking.
// B=16, H=768, W=1024, C=4 (C=4 floats -> one float4 per pixel).
//
// Semantics (match JAX reference exactly):
//   warp_y = y + flow[...,0]; warp_x = x + flow[...,1]
//   x0=floor(wx), x1=ceil(wx)  (ceil, NOT x0+1 -- integer coords on the edge)
//   output = bilinear(taps) * mask, mask = all(0 <= warp <= dim-1)
//
// V3 vs V2 (560 us harness / 302 us rocprof, VALUBusy 8%, HBM 15%, VGPR 20):
//   Counters showed a latency-bound gather: everything idle, and VGPR=20
//   proves the compiler serialized each pixel's taps behind the `if(valid)`
//   branch (~4 loads in flight per wave).
//   1. BRANCHLESS: clamp warp coords into bounds, gather unconditionally,
//      multiply result by valid-mask. Valid pixels: clamp is identity ->
//      bit-exact. Invalid pixels: finite garbage * 0.0 = exact 0.
//      (NaN flow would clamp via fminf/fmaxf to 0 and is masked anyway.)
//   2. PHASED: issue both rows' flow loads, then compute all addresses,
//      then issue ALL 8 tap loads back-to-back, then FMA+store.
//      Per-wave outstanding gathers 4 -> 8 at VGPR <= 64 (keeps the
//      8-waves/SIMD occupancy tier) -> 2x memory-level parallelism.
//   3. Tile 64x8, 2 rows/thread (RPT=2): full batch fits the VGPR budget.
// Kept from V2: 2D tiles for tap clustering, bijective XCD-chunked swizzle,
// non-temporal flow/out streams, hardcoded dims.

typedef float v2f __attribute__((ext_vector_type(2)));
typedef float v4f __attribute__((ext_vector_type(4)));

constexpr int B = 16, H = 768, W = 1024;
constexpr int TX = 64;                 // tile width  (= 1 wave per row)
constexpr int TY = 8;                  // tile height
constexpr int RPT = 2;                 // rows per thread (4 waves x 2 rows)
constexpr int XT = W / TX;             // 16 x-tiles
constexpr int YT = H / TY;             // 96 y-tiles
constexpr int NWG = B * XT * YT;       // 24576 workgroups
constexpr int NXCD = 8;
constexpr int CHUNK = NWG / NXCD;      // 3072 (exact -> swizzle bijective)

__global__ __launch_bounds__(256) void warp_bilinear_kernel(
    const float* __restrict__ src,   // [B,H,W,4]
    const float* __restrict__ flow,  // [B,H,W,2]
    float* __restrict__ out)         // [B,H,W,4]
{
    // XCD-aware chunked swizzle: give XCD k the contiguous tile range
    // [k*CHUNK, (k+1)*CHUNK) so its private L2 works one band of tiles.
    unsigned orig = blockIdx.x;
    unsigned t = (orig & (NXCD - 1)) * CHUNK + (orig >> 3);

    int xt = t & (XT - 1);             // x-tile (fastest -> row-major bands)
    unsigned tt = t >> 4;              // XT == 16
    int yt = (int)(tt % YT);
    int b  = (int)(tt / YT);

    int tx = threadIdx.x & 63;         // x within tile
    int wv = threadIdx.x >> 6;         // wave id 0..3

    int x     = (xt << 6) + tx;
    int ybase = yt * TY + wv * RPT;

    const v4f* sb = (const v4f*)src + b * (H * W);
    const v2f* fb = (const v2f*)flow;
    v4f*       ob = (v4f*)out;

    float xf  = (float)x;
    int  pix0 = (b * H + ybase) * W + x;

    // ---- phase 1: issue all flow loads ----
    v2f fl[RPT];
#pragma unroll
    for (int r = 0; r < RPT; ++r)
        fl[r] = __builtin_nontemporal_load(fb + pix0 + r * W);

    // ---- phase 2: addresses + weights (branchless, clamped) ----
    int   o00[RPT], o01[RPT], o10[RPT], o11[RPT];
    float wl[RPT], wr[RPT], wu[RPT], wd[RPT], vm[RPT];
#pragma unroll
    for (int r = 0; r < RPT; ++r) {
        float wy = (float)(ybase + r) + fl[r].x;
        float wx = xf                 + fl[r].y;

        bool valid = (wy >= 0.f) & (wy <= (float)(H - 1)) &
                     (wx >= 0.f) & (wx <= (float)(W - 1));
        vm[r] = valid ? 1.f : 0.f;

        // clamp into bounds: identity for valid pixels, safe garbage else
        float cy = fminf(fmaxf(wy, 0.f), (float)(H - 1));
        float cx = fminf(fmaxf(wx, 0.f), (float)(W - 1));

        float fx = floorf(cx);
        float fy = floorf(cy);
        int x0 = (int)fx;
        int y0 = (int)fy;
        int x1 = (int)ceilf(cx);
        int y1 = (int)ceilf(cy);
        wr[r] = cx - fx;               // w_right
        wd[r] = cy - fy;               // w_down
        wl[r] = 1.f - wr[r];           // w_left
        wu[r] = 1.f - wd[r];           // w_up

        o00[r] = y0 * W + x0;
        o01[r] = y0 * W + x1;
        o10[r] = y1 * W + x0;
        o11[r] = y1 * W + x1;
    }

    // ---- phase 3: issue ALL tap gathers back-to-back (8 in flight) ----
    v4f g00[RPT], g01[RPT], g10[RPT], g11[RPT];
#pragma unroll
    for (int r = 0; r < RPT; ++r) {
        g00[r] = sb[o00[r]];
        g01[r] = sb[o01[r]];
        g10[r] = sb[o10[r]];
        g11[r] = sb[o11[r]];
    }

    // ---- phase 4: interpolate, mask, store ----
#pragma unroll
    for (int r = 0; r < RPT; ++r) {
        v4f res = ((g00[r] * wl[r] + g01[r] * wr[r]) * wu[r]
                 + (g10[r] * wl[r] + g11[r] * wr[r]) * wd[r]) * vm[r];
        __builtin_nontemporal_store(res, ob + pix0 + r * W);
    }
}

extern "C" void kernel_launch(void* const* d_in, const int* in_sizes, int n_in,
                              void* d_out, int out_size, void* d_ws, size_t ws_size,
                              hipStream_t stream) {
    const float* src  = (const float*)d_in[0];  // [B,H,W,4] fp32
    const float* flow = (const float*)d_in[1];  // [B,H,W,2] fp32
    float* out = (float*)d_out;

    warp_bilinear_kernel<<<NWG, 256, 0, stream>>>(src, flow, out);
}